// Round 14
// baseline (280.345 us; speedup 1.0000x reference)
//
#include <hip/hip_runtime.h>

#define NTOK 343
#define NPAD 352
#define DIM 384
#define NHEAD 12
#define HDIM 32
#define NWIN 64
#define BATCH 128
#define SCALE 0.17677669529663687f
#define LOG2E 1.4426950408889634f
#define SCLG2 (0.17677669529663687f * 1.4426950408889634f)
#define NN 117649   // 343*343
#define MG 88       // NPAD/4 m-groups
#define GSTRIDE 1372  // NTOK*4 elems per m-group

typedef __attribute__((ext_vector_type(8))) short bf16x8;
typedef __attribute__((ext_vector_type(4))) short bf16x4;
typedef __attribute__((ext_vector_type(4))) float f32x4;
typedef __attribute__((ext_vector_type(4))) int i32x4;

static __device__ inline short f2bf(float f) {
  union { float f; unsigned u; } v; v.f = f;
  unsigned r = v.u + 0x7fffu + ((v.u >> 16) & 1u);
  return (short)(r >> 16);
}
static __device__ inline float bf2f(short s) {
  union { unsigned u; float f; } v; v.u = ((unsigned)(unsigned short)s) << 16;
  return v.f;
}
// fast pack: +0x8000 round-to-nearest, v_perm grabs the two high halves (3 VALU).
static __device__ inline int pack2rn(float lo, float hi) {
  union { float f; unsigned u; } a, b;
  a.f = lo; b.f = hi;
  unsigned au = a.u + 0x8000u;
  unsigned bu = b.u + 0x8000u;
  return (int)__builtin_amdgcn_perm(bu, au, 0x07060302u);
}
static __device__ inline short f2bfrn(float f) {
  union { float f; unsigned u; } v; v.f = f;
  return (short)((v.u + 0x8000u) >> 16);
}
// raw v_exp_f32 (exp2) — inputs are pre-scaled by LOG2E in prep kernels
static __device__ inline float fexp2(float x) {
  return __builtin_amdgcn_exp2f(x);
}

#define MFMA16(a, b, c) __builtin_amdgcn_mfma_f32_16x16x32_bf16((a), (b), (c), 0, 0, 0)

// ---- kernel 0a: bias_b4[h][g][q][r] = bf16(LOG2E*table[rpi[q][g*4+r]][h]) ---
__global__ __launch_bounds__(256) void bias_pk_kernel(
    const float* __restrict__ table, const int* __restrict__ rpi,
    short* __restrict__ bias_b4) {
  int idx = blockIdx.x * 256 + threadIdx.x;
  const int total = NHEAD * MG * NTOK * 4;
  if (idx >= total) return;
  int r = idx & 3;
  int t = idx >> 2;
  int q = t % NTOK;
  int u = t / NTOK;
  int g = u % MG;
  int h = u / MG;
  int m = g * 4 + r;
  bias_b4[idx] = (m < NTOK) ? f2bf(table[rpi[q * NTOK + m] * NHEAD + h] * LOG2E)
                            : f2bf(-1e30f);
}

// ---- kernel 0b: mask_b4[w][g][q][r] = bf16(LOG2E*mask[w][q][g*4+r]), pad=0 --
__global__ __launch_bounds__(256) void mask_pk_kernel(
    const float* __restrict__ in, short* __restrict__ mask_b4) {
  int idx = blockIdx.x * 256 + threadIdx.x;
  const int total = NWIN * MG * NTOK * 4;
  if (idx >= total) return;
  int r = idx & 3;
  int t = idx >> 2;
  int q = t % NTOK;
  int u = t / NTOK;
  int g = u % MG;
  int w = u / MG;
  int m = g * 4 + r;
  mask_b4[idx] = (m < NTOK) ? f2bf(in[(size_t)w * NN + q * NTOK + m] * LOG2E) : 0;
}

// ---- kernel 0c: skip f32 -> bf16 (A-operand for kv_proj) -------------------
__global__ __launch_bounds__(256) void cvt_skip_kernel(
    const float* __restrict__ in, short* __restrict__ out, int n8) {
  int i = blockIdx.x * 256 + threadIdx.x;
  if (i >= n8) return;
  f32x4 a = *(const f32x4*)(in + (size_t)i * 8);
  f32x4 b = *(const f32x4*)(in + (size_t)i * 8 + 4);
  bf16x8 o;
#pragma unroll
  for (int j = 0; j < 4; ++j) {
    o[j] = f2bf(a[j]);
    o[j + 4] = f2bf(b[j]);
  }
  *(bf16x8*)(out + (size_t)i * 8) = o;
}

// ---------- kernel 1: kv = skip_bf @ w_kv^T + b_kv -> K_ws/V_ws (bf16) ------
__global__ __launch_bounds__(256) void kv_proj_kernel(
    const short* __restrict__ Xbf, const float* __restrict__ W,
    const float* __restrict__ bkv, short* __restrict__ Kws,
    short* __restrict__ Vws) {
  __shared__ short As[128][40];
  __shared__ short Bs[128][40];
  const int L = blockIdx.x;            // 0..2057; XCD = L & 7
  const int xcd = L & 7;
  const int j8 = L >> 3;
  // 2058 = 8*257 + 2 -> xcd 0,1 get 258, others 257 (bijective)
  const int wg = ((xcd < 2) ? xcd * 258 : 516 + (xcd - 2) * 257) + j8;
  const int n0 = (wg % 6) * 128;
  const int m0 = (wg / 6) * 128;
  const int tid = threadIdx.x;
  const int lane = tid & 63;
  const int wave = tid >> 6;
  const int wm = (wave >> 1) * 64;
  const int wn = (wave & 1) * 64;
  const int lr = lane & 15;
  const int lk = (lane >> 4) * 8;
  const int c4 = (tid & 7) * 4;
  const int rbase = tid >> 3;
  const int arow = tid >> 2;        // 0..63
  const int acol8 = (tid & 3) * 8;  // 0,8,16,24
  const f32x4 zero4 = {0.f, 0.f, 0.f, 0.f};

  f32x4 acc[4][4];
#pragma unroll
  for (int m = 0; m < 4; ++m)
#pragma unroll
    for (int n = 0; n < 4; ++n) acc[m][n] = zero4;

  for (int kk = 0; kk < 12; ++kk) {
    __syncthreads();
    *(bf16x8*)(&As[arow][acol8]) =
        *(const bf16x8*)(Xbf + (size_t)(m0 + arow) * DIM + kk * 32 + acol8);
    *(bf16x8*)(&As[arow + 64][acol8]) =
        *(const bf16x8*)(Xbf + (size_t)(m0 + arow + 64) * DIM + kk * 32 + acol8);
#pragma unroll
    for (int i = 0; i < 4; ++i) {
      int row = rbase + i * 32;
      f32x4 v = *(const f32x4*)(W + (size_t)(n0 + row) * DIM + kk * 32 + c4);
      bf16x4 s4;
#pragma unroll
      for (int j = 0; j < 4; ++j) s4[j] = f2bf(v[j]);
      *(bf16x4*)(&Bs[row][c4]) = s4;
    }
    __syncthreads();
    bf16x8 af[4], bf[4];
#pragma unroll
    for (int m = 0; m < 4; ++m) af[m] = *(const bf16x8*)(&As[wm + m * 16 + lr][lk]);
#pragma unroll
    for (int n = 0; n < 4; ++n) bf[n] = *(const bf16x8*)(&Bs[wn + n * 16 + lr][lk]);
#pragma unroll
    for (int m = 0; m < 4; ++m)
#pragma unroll
      for (int n = 0; n < 4; ++n) acc[m][n] = MFMA16(af[m], bf[n], acc[m][n]);
  }

  const int rq = (lane >> 4) * 4;
#pragma unroll
  for (int n = 0; n < 4; ++n) {
    int gcol = n0 + wn + n * 16 + lr;
    float bias = bkv[gcol];
    int c = (gcol >= DIM) ? (gcol - DIM) : gcol;  // gcol % 384
    int h = c >> 5;
    int hd = c & 31;
    short* dst = (gcol < DIM) ? Kws : Vws;
#pragma unroll
    for (int m = 0; m < 4; ++m) {
#pragma unroll
      for (int r = 0; r < 4; ++r) {
        int grow = m0 + wm + m * 16 + rq + r;
        int bb = grow / NTOK;
        int tok = grow - bb * NTOK;
        dst[(((size_t)bb * NHEAD + h) * NTOK + tok) * HDIM + hd] =
            f2bf(acc[m][n][r] + bias);
      }
    }
  }
}

// ---------- kernel 2: fused attention per (b, h) — swapped-QK^T form --------
// This round: (1) bias+mask folded into MFMA C-in (matrix pipe does the add),
// (2) no max-subtraction (log2-domain logits bounded ~|16| -> exp2/f32 safe;
//     deferred normalization already proven R13),
// (3) XOR bank-swizzle on Ksm & Vp: col ^= (row&8) both sides; read-side XOR
//     hoisted into koff_s (zero hot-loop cost). Kills r<->r+8 2-way aliasing.
__global__ __launch_bounds__(256, 3) void attn_kernel(
    const float* __restrict__ x_up, const short* __restrict__ mask_b4,
    const short* __restrict__ bias_b4, const short* __restrict__ Kws,
    const short* __restrict__ Vws, const float* __restrict__ pos,
    short* __restrict__ attn_out) {
  __shared__ short Ksm[NPAD][40];      // K[key][ch], col ^= (key&8)
  __shared__ short Vp[HDIM][NPAD + 8]; // V^T[ch][pi(key) ^ (ch&8)]
  const int bid = blockIdx.x;
  const int xcd = bid & 7;
  const int jj = bid >> 3;                 // 0..191
  const int win = xcd * 8 + jj / 24;       // 0..63, pinned to xcd
  const int rep = jj - (jj / 24) * 24;     // 0..23
  const int h = rep % NHEAD;
  const int b = win + ((rep >= NHEAD) ? 64 : 0);
  const int tid = threadIdx.x;
  const int wave = tid >> 6;
  const int lane = tid & 63;
  const int lr = lane & 15;
  const int lg = lane >> 4;
  const int koff = lg * 8;
  const int koff_s = koff ^ (lane & 8);    // swizzled read col (row bit3 = lane bit3)
  const f32x4 zero4 = {0.f, 0.f, 0.f, 0.f};

  const short* Kb = Kws + ((size_t)b * NHEAD + h) * NTOK * HDIM;
  const short* Vb = Vws + ((size_t)b * NHEAD + h) * NTOK * HDIM;
  {
    const int c8 = (tid & 3) * 8;
    const int rb = tid >> 2;
    const bf16x8 z8 = {0, 0, 0, 0, 0, 0, 0, 0};
#pragma unroll
    for (int r0 = 0; r0 < 384; r0 += 64) {
      int row = r0 + rb;
      if (row < NPAD) {
        bf16x8 kv = z8;
        if (row < NTOK) kv = *(const bf16x8*)(Kb + row * HDIM + c8);
        *(bf16x8*)(&Ksm[row][c8 ^ (row & 8)]) = kv;  // write-side swizzle
      }
    }
#pragma unroll
    for (int r0 = 0; r0 < 384; r0 += 64) {
      int row = r0 + rb;
      if (row < NPAD) {
        bf16x8 vv = z8;
        if (row < NTOK) vv = *(const bf16x8*)(Vb + row * HDIM + c8);
        // pi(row): k-slot = ((m&16)>>2) | ((m&12)<<1) | (m&3) within 32-block
        int p = (row & ~31) | ((row & 12) << 1) | ((row & 16) >> 2) | (row & 3);
#pragma unroll
        for (int i = 0; i < 8; ++i)
          Vp[c8 + i][p ^ ((c8 + i) & 8)] = vv[i];    // write-side swizzle
      }
    }
  }
  __syncthreads();

  for (int qt = 0; qt < 6; ++qt) {
    const int q0 = qt * 64 + wave * 16;
    if (q0 >= NTOK) continue;
    const int qn = q0 + lr;
    const int qidx = (qn < NTOK) ? qn : (NTOK - 1);
    // Q B-frag scaled by SCALE*LOG2E (exp2 domain)
    bf16x8 qf;
    {
      const float* qp = x_up + ((size_t)b * NTOK + qidx) * DIM + h * HDIM + koff;
      f32x4 v0 = *(const f32x4*)qp;
      f32x4 v1 = *(const f32x4*)(qp + 4);
#pragma unroll
      for (int i = 0; i < 4; ++i) {
        qf[i] = f2bfrn(v0[i] * SCLG2);
        qf[i + 4] = f2bfrn(v1[i] * SCLG2);
      }
    }
    // bias+mask -> C-in (the MFMA adds them to QK^T on the matrix pipe)
    const short* bq = bias_b4 + (size_t)h * MG * GSTRIDE + (size_t)lg * GSTRIDE +
                      qidx * 4;
    const short* mq = mask_b4 + (size_t)win * MG * GSTRIDE + (size_t)lg * GSTRIDE +
                      qidx * 4;
    f32x4 s[22];
#pragma unroll
    for (int j = 0; j < 22; ++j) {
      bf16x4 bv = *(const bf16x4*)(bq + (size_t)j * 4 * GSTRIDE);
      bf16x4 mv = *(const bf16x4*)(mq + (size_t)j * 4 * GSTRIDE);
#pragma unroll
      for (int r = 0; r < 4; ++r) s[j][r] = bf2f(bv[r]) + bf2f(mv[r]);
    }
    // S^T tiles: s[j] = K_j * Q + (bias+mask)
    __builtin_amdgcn_s_setprio(1);
#pragma unroll
    for (int j = 0; j < 22; ++j) {
      bf16x8 kf = *(const bf16x8*)(&Ksm[j * 16 + lr][koff_s]);
      s[j] = MFMA16(kf, qf, s[j]);
    }
    __builtin_amdgcn_s_setprio(0);
    // p = exp2(s) directly (no max-sub; |s| bounded ~16 in log2 domain).
    // P packed UNNORMALIZED; sum via 4 independent chains.
    f32x4 sum4 = zero4;
    i32x4 up4[11];
#pragma unroll
    for (int j = 0; j < 22; ++j) {
      f32x4 p;
#pragma unroll
      for (int r = 0; r < 4; ++r) p[r] = fexp2(s[j][r]);
      sum4 += p;
      up4[j >> 1][(j & 1) * 2 + 0] = pack2rn(p[0], p[1]);
      up4[j >> 1][(j & 1) * 2 + 1] = pack2rn(p[2], p[3]);
    }
    float sum = (sum4[0] + sum4[1]) + (sum4[2] + sum4[3]);
    sum += __shfl_xor(sum, 16);
    sum += __shfl_xor(sum, 32);
    const float inv = 1.0f / sum;

    // O^T = V^T_pi * P~ (unnormalized): A-frag from Vp, B-frag = packed P regs
    f32x4 o0 = zero4;
    f32x4 o1 = zero4;
    __builtin_amdgcn_s_setprio(1);
#pragma unroll
    for (int kt = 0; kt < 11; ++kt) {
      bf16x8 pf = __builtin_bit_cast(bf16x8, up4[kt]);
      bf16x8 a0 = *(const bf16x8*)(&Vp[lr][kt * 32 + koff_s]);
      bf16x8 a1 = *(const bf16x8*)(&Vp[16 + lr][kt * 32 + koff_s]);
      o0 = MFMA16(a0, pf, o0);
      o1 = MFMA16(a1, pf, o1);
    }
    __builtin_amdgcn_s_setprio(0);
    // O is UNNORMALIZED (P~ packed before dividing by sum) -> the *inv in the
    // epilogue below is REQUIRED, exactly once. (R9 bug was the opposite.)
    if (qn < NTOK) {
      const float* pp = pos + ((size_t)b * NTOK + qn) * DIM + h * HDIM + 4 * lg;
      f32x4 p0 = *(const f32x4*)pp;
      f32x4 p1 = *(const f32x4*)(pp + 16);
      short* op = attn_out + ((size_t)b * NTOK + qn) * DIM + h * HDIM + 4 * lg;
      *(int*)(op + 0) = pack2rn(o0[0] * inv + p0[0], o0[1] * inv + p0[1]);
      *(int*)(op + 2) = pack2rn(o0[2] * inv + p0[2], o0[3] * inv + p0[3]);
      *(int*)(op + 16) = pack2rn(o1[0] * inv + p1[0], o1[1] * inv + p1[1]);
      *(int*)(op + 18) = pack2rn(o1[2] * inv + p1[2], o1[3] * inv + p1[3]);
    }
  }
}

// ---------- kernel 3: out = Xa @ w_proj^T + b_proj (Xa = attn+pos, bf16) ----
__global__ __launch_bounds__(256) void out_proj_kernel(
    const short* __restrict__ Xa, const float* __restrict__ W,
    const float* __restrict__ bpr, float* __restrict__ out) {
  __shared__ short As[128][40];
  __shared__ short Bs[128][40];
  const int L = blockIdx.x;            // 0..1028
  const int xcd = L & 7;
  const int j8 = L >> 3;
  // 1029 = 8*128 + 5 -> xcd 0..4 get 129, others 128 (bijective)
  const int wg = ((xcd < 5) ? xcd * 129 : 645 + (xcd - 5) * 128) + j8;
  const int n0 = (wg % 3) * 128;
  const int m0 = (wg / 3) * 128;
  const int tid = threadIdx.x;
  const int lane = tid & 63;
  const int wave = tid >> 6;
  const int wm = (wave >> 1) * 64;
  const int wn = (wave & 1) * 64;
  const int lr = lane & 15;
  const int lk = (lane >> 4) * 8;
  const int c4 = (tid & 7) * 4;
  const int rbase = tid >> 3;
  const int arow = tid >> 2;
  const int acol8 = (tid & 3) * 8;
  const f32x4 zero4 = {0.f, 0.f, 0.f, 0.f};

  f32x4 acc[4][4];
#pragma unroll
  for (int m = 0; m < 4; ++m)
#pragma unroll
    for (int n = 0; n < 4; ++n) acc[m][n] = zero4;

  for (int kk = 0; kk < 12; ++kk) {
    __syncthreads();
    *(bf16x8*)(&As[arow][acol8]) =
        *(const bf16x8*)(Xa + (size_t)(m0 + arow) * DIM + kk * 32 + acol8);
    *(bf16x8*)(&As[arow + 64][acol8]) =
        *(const bf16x8*)(Xa + (size_t)(m0 + arow + 64) * DIM + kk * 32 + acol8);
#pragma unroll
    for (int i = 0; i < 4; ++i) {
      int row = rbase + i * 32;
      f32x4 v = *(const f32x4*)(W + (size_t)(n0 + row) * DIM + kk * 32 + c4);
      bf16x4 s4;
#pragma unroll
      for (int j = 0; j < 4; ++j) s4[j] = f2bf(v[j]);
      *(bf16x4*)(&Bs[row][c4]) = s4;
    }
    __syncthreads();
    bf16x8 af[4], bf[4];
#pragma unroll
    for (int m = 0; m < 4; ++m) af[m] = *(const bf16x8*)(&As[wm + m * 16 + lr][lk]);
#pragma unroll
    for (int n = 0; n < 4; ++n) bf[n] = *(const bf16x8*)(&Bs[wn + n * 16 + lr][lk]);
#pragma unroll
    for (int m = 0; m < 4; ++m)
#pragma unroll
      for (int n = 0; n < 4; ++n) acc[m][n] = MFMA16(af[m], bf[n], acc[m][n]);
  }

  const int rq = (lane >> 4) * 4;
#pragma unroll
  for (int n = 0; n < 4; ++n) {
    int gcol = n0 + wn + n * 16 + lr;
    float bias = bpr[gcol];
#pragma unroll
    for (int m = 0; m < 4; ++m) {
#pragma unroll
      for (int r = 0; r < 4; ++r) {
        int grow = m0 + wm + m * 16 + rq + r;
        out[(size_t)grow * DIM + gcol] = acc[m][n][r] + bias;
      }
    }
  }
}

extern "C" void kernel_launch(void* const* d_in, const int* in_sizes, int n_in,
                              void* d_out, int out_size, void* d_ws, size_t ws_size,
                              hipStream_t stream) {
  const float* skip = (const float*)d_in[0];
  const float* x_up = (const float*)d_in[1];
  const float* pos = (const float*)d_in[2];
  const float* mask = (const float*)d_in[3];
  const float* w_kv = (const float*)d_in[4];
  const float* b_kv = (const float*)d_in[5];
  const float* w_proj = (const float*)d_in[6];
  const float* b_proj = (const float*)d_in[7];
  const float* bias_table = (const float*)d_in[8];
  const int* rpi = (const int*)d_in[9];
  float* out = (float*)d_out;

  char* ws = (char*)d_ws;
  const size_t kv_bytes = (size_t)BATCH * NHEAD * NTOK * HDIM * 2;   // 33,718,272
  const size_t bias_bytes = (size_t)NHEAD * MG * NTOK * 4 * 2;       //  2,897,664
  const size_t mask_bytes = (size_t)NWIN * MG * NTOK * 4 * 2;        // 15,454,208
  short* Kws = (short*)ws;
  short* Vws = (short*)(ws + kv_bytes);
  short* bias_b4 = (short*)(ws + 2 * kv_bytes);
  short* mask_b4 = (short*)(ws + 2 * kv_bytes + bias_bytes);
  // skip_bf and attn_ws alias: cvt_skip->kv_proj finish before attn writes it
  short* skip_bf = (short*)(ws + 2 * kv_bytes + bias_bytes + mask_bytes);
  short* attn_ws = skip_bf;

  const int bias_total = NHEAD * MG * NTOK * 4;
  const int mask_total = NWIN * MG * NTOK * 4;
  const int n8 = BATCH * NTOK * DIM / 8;  // 2,107,392
  bias_pk_kernel<<<dim3((bias_total + 255) / 256), dim3(256), 0, stream>>>(
      bias_table, rpi, bias_b4);
  mask_pk_kernel<<<dim3((mask_total + 255) / 256), dim3(256), 0, stream>>>(
      mask, mask_b4);
  cvt_skip_kernel<<<dim3((n8 + 255) / 256), dim3(256), 0, stream>>>(
      skip, skip_bf, n8);
  kv_proj_kernel<<<dim3(2058), dim3(256), 0, stream>>>(skip_bf, w_kv, b_kv,
                                                       Kws, Vws);
  attn_kernel<<<dim3(BATCH * NHEAD), dim3(256), 0, stream>>>(
      x_up, mask_b4, bias_b4, Kws, Vws, pos, attn_ws);
  out_proj_kernel<<<dim3(1029), dim3(256), 0, stream>>>(attn_ws, w_proj,
                                                        b_proj, out);
}